// Round 3
// baseline (240.566 us; speedup 1.0000x reference)
//
#include <hip/hip_runtime.h>

#define KK 21
#define HH 512
#define WW 512
#define CC 3
#define BB 32
#define TILE_Y 64
#define TILE_X 128
#define SROWS 85        // 2-kh packing reads rows up to 16*3+15+21 = 84
#define SSTRIDE 168     // ushort elems/row; 336 B = odd multiple of 16B -> conflict-free reads
#define NKHP 11         // ceil(21/2) kh-pairs; kh=21 is a zero row in B
#define NB_PER_B (NKHP * 3 * 512)   // 16896 bf16 elems per batch
#define NCHUNK 20       // 8-ushort (16B) staging chunks per row: lc in [0,160)
#define NSTG (SROWS * NCHUNK)       // 1700 staged chunks per tile
#define NT 4            // x-tiles per block (one horizontal strip)
#define NBLK (BB * CC * (HH / TILE_Y))   // 768 blocks = 3/CU exactly

typedef __attribute__((ext_vector_type(8))) short short8;
typedef __attribute__((ext_vector_type(4))) float floatx4;

__device__ __forceinline__ unsigned short f2bf(float f) {
    union { float f; unsigned u; } v; v.f = f;
    unsigned r = v.u + 0x7FFF + ((v.u >> 16) & 1);   // RNE
    return (unsigned short)(r >> 16);
}

// ---- kernel 1: build banded-Toeplitz B fragments (2 kernel rows packed per K=32) ----
// el = khp*1536 + half*512 + (q*16 + n)*8 + j   (bf16)
// k = q*8+j; h = k>>4 (selects kernel row 2*khp+h); c = k&15
// tap d = c - n - 2 + 16*half  (staged origin gx = tx0 - 12 + lc)
__global__ __launch_bounds__(256) void build_B(
    const float* __restrict__ ker, unsigned short* __restrict__ wsB)
{
    const int b = blockIdx.x;
    const float* __restrict__ kp = ker + b * KK * KK;
    unsigned short* __restrict__ wb = wsB + (size_t)b * NB_PER_B;
    for (int e = threadIdx.x; e < NB_PER_B; e += 256) {
        const int j    = e & 7;
        const int n    = (e >> 3) & 15;
        const int q    = (e >> 7) & 3;
        const int f    = e >> 9;           // khp*3 + half
        const int khp  = f / 3;
        const int half = f - khp * 3;
        const int k    = q * 8 + j;
        const int h    = k >> 4;
        const int c    = k & 15;
        const int kh   = 2 * khp + h;
        const int d    = c - n - 2 + 16 * half;
        float v = 0.0f;
        if (kh < KK && d >= 0 && d < KK) v = kp[kh * KK + d];
        wb[e] = f2bf(v);
    }
}

// ---- staged-load helpers: global->regs (issue early), regs->LDS (write late) ----
__device__ __forceinline__ void load_stage(
    const float* __restrict__ xp, int ty0, int tx0, int tid,
    float4 (&sv0)[7], float4 (&sv1)[7])
{
#pragma unroll
    for (int it = 0; it < 7; ++it) {
        const int i = tid + 256 * it;
        if (it == 6 && i >= NSTG) continue;            // 1700 = 256*6 + 164
        const int ly  = i / NCHUNK;
        const int k   = i - ly * NCHUNK;
        const int gy  = ty0 - 10 + ly;
        const int gx0 = tx0 - 12 + 8 * k;              // float4-aligned
        float4 v0 = make_float4(0.f, 0.f, 0.f, 0.f);
        float4 v1 = make_float4(0.f, 0.f, 0.f, 0.f);
        if (gy >= 0 && gy < HH) {
            const float* __restrict__ rp = xp + (size_t)gy * WW;
            if (gx0 >= 0 && gx0 + 7 < WW) {
                v0 = *(const float4*)(rp + gx0);
                v1 = *(const float4*)(rp + gx0 + 4);
            } else {
                if (gx0 + 0 >= 0 && gx0 + 0 < WW) v0.x = rp[gx0 + 0];
                if (gx0 + 1 >= 0 && gx0 + 1 < WW) v0.y = rp[gx0 + 1];
                if (gx0 + 2 >= 0 && gx0 + 2 < WW) v0.z = rp[gx0 + 2];
                if (gx0 + 3 >= 0 && gx0 + 3 < WW) v0.w = rp[gx0 + 3];
                if (gx0 + 4 >= 0 && gx0 + 4 < WW) v1.x = rp[gx0 + 4];
                if (gx0 + 5 >= 0 && gx0 + 5 < WW) v1.y = rp[gx0 + 5];
                if (gx0 + 6 >= 0 && gx0 + 6 < WW) v1.z = rp[gx0 + 6];
                if (gx0 + 7 >= 0 && gx0 + 7 < WW) v1.w = rp[gx0 + 7];
            }
        }
        sv0[it] = v0;
        sv1[it] = v1;
    }
}

__device__ __forceinline__ void cvt_write(
    unsigned short* __restrict__ s_in, int tid,
    const float4 (&sv0)[7], const float4 (&sv1)[7])
{
#pragma unroll
    for (int it = 0; it < 7; ++it) {
        const int i = tid + 256 * it;
        if (it == 6 && i >= NSTG) continue;
        const int ly = i / NCHUNK;
        const int k  = i - ly * NCHUNK;
        const int p0 = (int)((unsigned)f2bf(sv0[it].x) | ((unsigned)f2bf(sv0[it].y) << 16));
        const int p1 = (int)((unsigned)f2bf(sv0[it].z) | ((unsigned)f2bf(sv0[it].w) << 16));
        const int p2 = (int)((unsigned)f2bf(sv1[it].x) | ((unsigned)f2bf(sv1[it].y) << 16));
        const int p3 = (int)((unsigned)f2bf(sv1[it].z) | ((unsigned)f2bf(sv1[it].w) << 16));
        *(int4*)&s_in[ly * SSTRIDE + 8 * k] = make_int4(p0, p1, p2, p3);  // 16B aligned
    }
}

// ---- kernel 2: main MFMA conv; each block pipelines a strip of 4 x-tiles ----
__global__ __launch_bounds__(256, 3) void dwconv_mfma(
    const float* __restrict__ x,
    const unsigned short* __restrict__ wsB,
    float* __restrict__ out)
{
    __shared__ __align__(16) unsigned short s_in[SROWS * SSTRIDE];  // 28560 B

    // bijective XCD-aware remap: 768 = 8 XCDs * 96; XCD x gets rbid [96x, 96x+96)
    const int rbid = (blockIdx.x & 7) * (NBLK / 8) + (blockIdx.x >> 3);
    const int bc   = rbid >> 3;              // 0..95 (image*channel)
    const int ty0  = (rbid & 7) * TILE_Y;    // tile-row strip
    const int b    = bc / CC;

    const float* __restrict__ xp = x + (size_t)bc * HH * WW;
    float* __restrict__ op = out + (size_t)bc * HH * WW;
    const unsigned short* __restrict__ wsb = wsB + (size_t)b * NB_PER_B;
    const int tid = threadIdx.x;

    const int lane = tid & 63;
    const int wv   = tid >> 6;       // wave 0..3 -> output rows 16*wv..+15
    const int mrow = lane & 15;      // A's m / B's n / D's col
    const int qd   = lane >> 4;      // k-chunk: h = qd>>1 (kernel row), col half = qd&1

    const unsigned short* bbase = wsb + lane * 8;
    const unsigned short* abase = s_in + ((16 * wv + mrow + (qd >> 1)) * SSTRIDE) + 8 * (qd & 1);

    float4 sv0[7], sv1[7];

    // prologue: stage tile 0
    load_stage(xp, ty0, 0, tid, sv0, sv1);
    cvt_write(s_in, tid, sv0, sv1);
    __syncthreads();

    for (int t0 = 0; t0 < NT; ++t0) {
        const int tx0 = t0 * TILE_X;

        // issue next tile's global loads now; HBM latency hides under the khp loop
        if (t0 + 1 < NT)
            load_stage(xp, ty0, tx0 + TILE_X, tid, sv0, sv1);

        floatx4 acc[8];
#pragma unroll
        for (int tt = 0; tt < 8; ++tt) acc[tt] = (floatx4){0.f, 0.f, 0.f, 0.f};

        short8 nb1 = *(const short8*)(bbase);
        short8 nb2 = *(const short8*)(bbase + 512);
        short8 nb3 = *(const short8*)(bbase + 1024);

#pragma unroll 1
        for (int khp = 0; khp < NKHP; ++khp) {
            const short8 b1 = nb1;
            const short8 b2 = nb2;
            const short8 b3 = nb3;
            const int khn = (khp < NKHP - 1) ? (khp + 1) : khp;   // clamped prefetch
            nb1 = *(const short8*)(bbase + khn * 1536);
            nb2 = *(const short8*)(bbase + khn * 1536 + 512);
            nb3 = *(const short8*)(bbase + khn * 1536 + 1024);

            const unsigned short* arow = abase + 2 * khp * SSTRIDE;
            short8 a[10];
#pragma unroll
            for (int s = 0; s < 10; ++s) a[s] = *(const short8*)(arow + 16 * s);

#pragma unroll
            for (int tt = 0; tt < 8; ++tt) {
                acc[tt] = __builtin_amdgcn_mfma_f32_16x16x32_bf16(a[tt],     b1, acc[tt], 0, 0, 0);
                acc[tt] = __builtin_amdgcn_mfma_f32_16x16x32_bf16(a[tt + 1], b2, acc[tt], 0, 0, 0);
                acc[tt] = __builtin_amdgcn_mfma_f32_16x16x32_bf16(a[tt + 2], b3, acc[tt], 0, 0, 0);
            }
        }

        // epilogue: D layout col=lane&15, row=(lane>>4)*4+reg
#pragma unroll
        for (int tt = 0; tt < 8; ++tt) {
#pragma unroll
            for (int r = 0; r < 4; ++r) {
                const int y = ty0 + 16 * wv + qd * 4 + r;
                const int xcol = tx0 + 16 * tt + mrow;
                op[(size_t)y * WW + xcol] = acc[tt][r];
            }
        }

        if (t0 + 1 < NT) {
            __syncthreads();                 // all waves done reading s_in
            cvt_write(s_in, tid, sv0, sv1);  // loads have drained during compute
            __syncthreads();                 // writes visible before next compute
        }
    }
}

extern "C" void kernel_launch(void* const* d_in, const int* in_sizes, int n_in,
                              void* d_out, int out_size, void* d_ws, size_t ws_size,
                              hipStream_t stream) {
    const float* x   = (const float*)d_in[0];
    const float* ker = (const float*)d_in[1];
    float* out = (float*)d_out;
    unsigned short* wsB = (unsigned short*)d_ws;   // 32*16896*2 = 1,081,344 B

    build_B<<<BB, 256, 0, stream>>>(ker, wsB);

    dwconv_mfma<<<NBLK, 256, 0, stream>>>(x, wsB, out);
}